// Round 1
// baseline (94.754 us; speedup 1.0000x reference)
//
#include <hip/hip_runtime.h>

#define B_SZ 16384
#define D_IN 65
#define N_SP 129

#define QSTRIDE 68
#define WS_QXT 0
#define WS_QTT 4352
#define WS_QXY 8704
#define WS_QYT 8768
#define WS_LINT 8832
#define WS_LINY 8896

#define GRID 512
#define BLOCK 256
#define NWAVES (GRID * BLOCK / 64) /* 2048 */
#define NGROUP (B_SZ / 4)          /* 4096 */

// index into main_w for quadratic pair (i<j), N=129: N + i*(2N-i-1)/2 + (j-i-1)
__device__ __forceinline__ int qidx(int i, int j) {
  return N_SP + i * (2 * N_SP - i - 1) / 2 + (j - i - 1);
}

__global__ void setup_kernel(const float* __restrict__ mw, float* __restrict__ ws,
                             float* __restrict__ out) {
  int t = blockIdx.x * blockDim.x + threadIdx.x;
  if (t == 0) { out[B_SZ] = 0.f; out[B_SZ + 1] = 0.f; }
  if (t < 4352) {
    int i = t / QSTRIDE, k = t % QSTRIDE;
    ws[WS_QXT + t] = (k < 64) ? mw[qidx(i, 65 + k)] : 0.f;
  } else if (t < 8704) {
    int r = t - 4352;
    int j = r / QSTRIDE, k = r % QSTRIDE;
    float v = 0.f;
    if (k < 64 && k != j) {
      int a = j < k ? j : k, b = j < k ? k : j;
      v = mw[qidx(65 + a, 65 + b)];
    }
    ws[WS_QTT + r] = v;
  } else if (t < 8768) {
    int i = t - 8704;
    ws[WS_QXY + i] = mw[qidx(i, 64)];
  } else if (t < 8832) {
    int k = t - 8768;
    ws[WS_QYT + k] = mw[qidx(64, 65 + k)];
  } else if (t < 8896) {
    int k = t - 8832;
    ws[WS_LINT + k] = mw[65 + k];
  } else if (t == 8896) {
    ws[WS_LINY] = mw[64];
  }
}

__device__ __forceinline__ float rdl(float v, int l) {
  return __int_as_float(__builtin_amdgcn_readlane(__float_as_int(v), l));
}

// tanh(x) = 1 - 2/(e^{2x}+1): monotone, stable both tails, no cancellation
__device__ __forceinline__ float fast_tanh(float x) {
  float xc = fminf(fmaxf(x, -15.f), 15.f);
  float e = __expf(2.f * xc);
  return 1.f - 2.f / (e + 1.f);
}

__global__ __launch_bounds__(BLOCK, 2) void main_kernel(
    const float* __restrict__ inps, const float* __restrict__ tw,
    const float* __restrict__ tb, const float* __restrict__ ws,
    float* __restrict__ out) {
  __shared__ float s_tw[4352];   // 64 rows, stride 68 (16B aligned, b128 conflict-free)
  __shared__ float s_qxt[4352];
  __shared__ float s_qtt[4352];
  __shared__ float s_qxy[64], s_qyt[64], s_lint[64], s_tb[64];
  __shared__ float s_red[8];

  const int tid = threadIdx.x;
  for (int idx = tid; idx < 4352; idx += BLOCK) {
    int i = idx / QSTRIDE, d = idx % QSTRIDE;
    s_tw[idx] = (d < 65) ? tw[i * 65 + d] : 0.f;
    s_qxt[idx] = ws[WS_QXT + idx];
    s_qtt[idx] = ws[WS_QTT + idx];
  }
  if (tid < 64) {
    s_qxy[tid] = ws[WS_QXY + tid];
    s_qyt[tid] = ws[WS_QYT + tid];
    s_lint[tid] = ws[WS_LINT + tid];
    s_tb[tid] = tb[tid];
  }
  __syncthreads();

  const int lane = tid & 63;
  const int wave_id = (blockIdx.x * BLOCK + tid) >> 6;
  const float liny = ws[WS_LINY];
  const float twy = s_tw[lane * QSTRIDE + 64];
  const float qxy = s_qxy[lane], qyt = s_qyt[lane];
  const float lint = s_lint[lane], tbv = s_tb[lane];

  float pint = 0.f, pneut = 0.f;

  for (int g = wave_id; g < NGROUP; g += NWAVES) {
    const int b0 = g * 4;
    float xv[4], yv[4], acc[4];
#pragma unroll
    for (int r = 0; r < 4; r++) {
      xv[r] = inps[(b0 + r) * D_IN + lane];   // lane l holds x_l of row r
      yv[r] = inps[(b0 + r) * D_IN + 64];     // uniform -> scalar load
      acc[r] = tbv;
    }
    // w1[a] (a = lane) over d=0..63; y-term added after (w2 = acc - twy*y)
#pragma unroll
    for (int d4 = 0; d4 < 64; d4 += 4) {
      const float4 w = *(const float4*)&s_tw[lane * QSTRIDE + d4];
#pragma unroll
      for (int r = 0; r < 4; r++) {
        acc[r] += w.x * rdl(xv[r], d4 + 0);
        acc[r] += w.y * rdl(xv[r], d4 + 1);
        acc[r] += w.z * rdl(xv[r], d4 + 2);
        acc[r] += w.w * rdl(xv[r], d4 + 3);
      }
    }
    float dt[4], st[4];
#pragma unroll
    for (int r = 0; r < 4; r++) {
      float w1 = acc[r] + twy * yv[r];
      float w2 = acc[r] - twy * yv[r];
      float t1 = fast_tanh(w1), t2 = fast_tanh(w2);
      dt[r] = t1 - t2;
      st[r] = t1 + t2;
      float a1 = 1.f - t1 * t1, a2 = 1.f - t2 * t2;
      pint += a1 * a1 + a2 * a2;
      float nv = t2 * w2 - t1 * w1;
      pneut += nv * nv;
    }
    float rxt[4] = {0.f, 0.f, 0.f, 0.f}, rtt[4] = {0.f, 0.f, 0.f, 0.f};
#pragma unroll
    for (int k4 = 0; k4 < 64; k4 += 4) {
      const float4 qx = *(const float4*)&s_qxt[lane * QSTRIDE + k4];
      const float4 qt = *(const float4*)&s_qtt[lane * QSTRIDE + k4];
#pragma unroll
      for (int r = 0; r < 4; r++) {
        float d0 = rdl(dt[r], k4 + 0), d1 = rdl(dt[r], k4 + 1);
        float d2 = rdl(dt[r], k4 + 2), d3 = rdl(dt[r], k4 + 3);
        rxt[r] += qx.x * d0 + qx.y * d1 + qx.z * d2 + qx.w * d3;
        rtt[r] += qt.x * d0 + qt.y * d1 + qt.z * d2 + qt.w * d3;
      }
    }
#pragma unroll
    for (int r = 0; r < 4; r++) {
      float c = 2.f * yv[r] * xv[r] * qxy + xv[r] * rxt[r] +
                yv[r] * st[r] * qyt + 0.5f * st[r] * rtt[r] + lint * dt[r];
#pragma unroll
      for (int off = 32; off > 0; off >>= 1) c += __shfl_down(c, off);
      if (lane == 0) out[b0 + r] = 1.f + 2.f * yv[r] * liny + c;
    }
  }

#pragma unroll
  for (int off = 32; off > 0; off >>= 1) {
    pint += __shfl_down(pint, off);
    pneut += __shfl_down(pneut, off);
  }
  const int widx = tid >> 6;
  if (lane == 0) {
    s_red[widx] = pint;
    s_red[4 + widx] = pneut;
  }
  __syncthreads();
  if (tid == 0) {
    float a = s_red[0] + s_red[1] + s_red[2] + s_red[3];
    float b = s_red[4] + s_red[5] + s_red[6] + s_red[7];
    atomicAdd(&out[B_SZ], a * (1.f / 300.f));
    atomicAdd(&out[B_SZ + 1], b);
  }
}

extern "C" void kernel_launch(void* const* d_in, const int* in_sizes, int n_in,
                              void* d_out, int out_size, void* d_ws, size_t ws_size,
                              hipStream_t stream) {
  const float* inps = (const float*)d_in[0];
  const float* tw   = (const float*)d_in[1];
  const float* tb   = (const float*)d_in[2];
  const float* mw   = (const float*)d_in[3];
  float* out = (float*)d_out;
  float* ws  = (float*)d_ws;
  setup_kernel<<<35, 256, 0, stream>>>(mw, ws, out);
  main_kernel<<<GRID, BLOCK, 0, stream>>>(inps, tw, tb, ws, out);
}